// Round 2
// baseline (1411.895 us; speedup 1.0000x reference)
//
#include <hip/hip_runtime.h>

// SparseSpikingConv2D: 3x3 SAME conv (Cin=64 -> Cout=128) + LIF + multi-threshold spike.
// Round 1: fp64 accumulation throughout. The spike output is a hard threshold;
// fp32 ordering noise (~1e-7 on mthr) flips ~4-8 of 16.7M pixels vs a float64
// numpy referee. fp64 accumulation is exact enough (products of fp32 values are
// exact in double) that spike decisions match the fp64 reference with
// probability ~1 - 1e-5.

constexpr int KKT = 9;    // K*K taps
constexpr int CI  = 64;
constexpr int CO  = 128;
constexpr int HH  = 64;
constexpr int WW  = 64;
constexpr int NB  = 32;

// Convert weights fp32 -> fp64 into workspace (uniform, L2-resident afterwards).
__global__ void cvt_w_kernel(const float* __restrict__ w, double* __restrict__ wd) {
    const int i = blockIdx.x * 256 + threadIdx.x;
    if (i < KKT * CI * CO) wd[i] = (double)w[i];
}

// normd[co] = sum_{k,ci} w^2 + 1e-8, all in fp64.
__global__ void norm_kernel(const float* __restrict__ w, double* __restrict__ normd) {
    const int co = threadIdx.x;  // 0..127
    double s = 0.0;
    for (int i = 0; i < KKT * CI; ++i) {
        const double v = (double)w[i * CO + co];
        s = fma(v, v, s);
    }
    normd[co] = s + 1e-8;
}

template <bool USE_WD>
__global__ __launch_bounds__(256) void conv_lif_kernel(
    const float*  __restrict__ x,       // [32,64,64,64]
    const float*  __restrict__ mem,     // [32,128,64,64]
    const float*  __restrict__ w32,     // [9,64,128] fp32 (fallback path)
    const double* __restrict__ wd,      // [9,64,128] fp64 (fast path)
    const float*  __restrict__ beta_p,  // [1]
    const float*  __restrict__ bias,    // [128]
    const double* __restrict__ normd,   // [128] = norm + 1e-8 (fp64)
    float* __restrict__ out_spk,        // [32,128,64,64]
    float* __restrict__ out_mem)        // [32,128,64,64]
{
    const int ix  = threadIdx.x;                    // 0..63 (coalesced along W)
    const int iy  = blockIdx.x * 4 + threadIdx.y;   // 0..63
    const int co0 = blockIdx.y * 4;                 // 0..124
    const int n   = blockIdx.z;                     // 0..31

    // 9 tap offsets + validity (loop-invariant over ci).
    bool valid[9];
    int  xoff[9];
    #pragma unroll
    for (int kh = 0; kh < 3; ++kh) {
        const int yy = iy + kh - 1;
        const bool yok = (unsigned)yy < (unsigned)HH;
        #pragma unroll
        for (int kw = 0; kw < 3; ++kw) {
            const int xx = ix + kw - 1;
            const int t = kh * 3 + kw;
            valid[t] = yok && ((unsigned)xx < (unsigned)WW);
            xoff[t]  = yy * WW + xx;
        }
    }

    double acc0 = 0.0, acc1 = 0.0, acc2 = 0.0, acc3 = 0.0;

    const float* xbase = x + (size_t)n * CI * HH * WW;

    for (int ci = 0; ci < CI; ++ci) {
        const float* xc = xbase + (size_t)ci * HH * WW;
        #pragma unroll
        for (int t = 0; t < 9; ++t) {
            const double xv = valid[t] ? (double)xc[xoff[t]] : 0.0;
            double w0, w1, w2, w3;
            if (USE_WD) {
                const double* wt = wd + (size_t)t * CI * CO + (size_t)ci * CO + co0;
                w0 = wt[0]; w1 = wt[1]; w2 = wt[2]; w3 = wt[3];
            } else {
                const float* wt = w32 + (size_t)t * CI * CO + (size_t)ci * CO + co0;
                w0 = (double)wt[0]; w1 = (double)wt[1];
                w2 = (double)wt[2]; w3 = (double)wt[3];
            }
            acc0 = fma(xv, w0, acc0);
            acc1 = fma(xv, w1, acc1);
            acc2 = fma(xv, w2, acc2);
            acc3 = fma(xv, w3, acc3);
        }
    }

    // Epilogue in fp64: LIF update + multi-threshold spike.
    const double beta = (double)beta_p[0];
    const double omb  = 1.0 - beta;
    const size_t plane = (size_t)HH * WW;
    const size_t base  = (((size_t)n * CO + co0) * HH + iy) * WW + ix;

    double accs[4] = {acc0, acc1, acc2, acc3};
    #pragma unroll
    for (int j = 0; j < 4; ++j) {
        const size_t idx = base + (size_t)j * plane;
        const double nm   = (double)mem[idx] * beta + accs[j] * omb;
        const double mthr = nm / normd[co0 + j] - (double)bias[co0 + j];
        const int s = (mthr > 0.0) + (mthr > 1.0) + (mthr > 2.0) + (mthr > 3.0);
        out_spk[idx] = (float)s;
        out_mem[idx] = (s > 0) ? 0.0f : (float)nm;
    }
}

extern "C" void kernel_launch(void* const* d_in, const int* in_sizes, int n_in,
                              void* d_out, int out_size, void* d_ws, size_t ws_size,
                              hipStream_t stream) {
    const float* x      = (const float*)d_in[0];
    const float* mem    = (const float*)d_in[1];
    const float* w      = (const float*)d_in[2];
    const float* beta_p = (const float*)d_in[3];
    const float* bias   = (const float*)d_in[4];
    // d_in[5] = bs (=32), compile-time constant here

    float* out_spk = (float*)d_out;
    float* out_mem = out_spk + (size_t)NB * CO * HH * WW;

    const size_t wd_bytes   = (size_t)KKT * CI * CO * sizeof(double); // 589,824
    const size_t norm_bytes = (size_t)CO * sizeof(double);            // 1,024
    const bool use_wd = ws_size >= wd_bytes + norm_bytes;

    double* wd;
    double* normd;
    if (use_wd) {
        wd    = (double*)d_ws;
        normd = (double*)((char*)d_ws + wd_bytes);
    } else {
        wd    = nullptr;
        normd = (double*)d_ws;  // needs only 1 KB
    }

    norm_kernel<<<1, CO, 0, stream>>>(w, normd);
    if (use_wd) {
        cvt_w_kernel<<<(KKT * CI * CO + 255) / 256, 256, 0, stream>>>(w, wd);
    }

    dim3 block(WW, 4, 1);               // 256 threads
    dim3 grid(HH / 4, CO / 4, NB);      // 16 x 32 x 32 blocks
    if (use_wd) {
        conv_lif_kernel<true><<<grid, block, 0, stream>>>(
            x, mem, w, wd, beta_p, bias, normd, out_spk, out_mem);
    } else {
        conv_lif_kernel<false><<<grid, block, 0, stream>>>(
            x, mem, w, wd, beta_p, bias, normd, out_spk, out_mem);
    }
}

// Round 3
// 1131.872 us; speedup vs baseline: 1.2474x; 1.2474x over previous
//
#include <hip/hip_runtime.h>

// SparseSpikingConv2D: 3x3 SAME conv (Cin=64 -> Cout=128) + LIF + multi-threshold spike.
// Round 2: fp64 accumulation (required: spike decisions referee'd against an
// fp64 numpy recompute; fp32 ordering noise flips ~5 of 16.7M spikes).
// Perf change vs R1: 8 Cout/thread (was 4) + ci-unroll(2) — amortizes the 9
// x-load/cvt/select over 72 dfma instead of 36, and gives the scheduler two
// independent scalar weight-load chains to hide lgkmcnt latency.
// fp64 dfma floor: 246 us.

constexpr int KKT = 9;    // K*K taps
constexpr int CI  = 64;
constexpr int CO  = 128;
constexpr int HH  = 64;
constexpr int WW  = 64;
constexpr int NB  = 32;

// Convert weights fp32 -> fp64 into workspace (re-run every launch; ws re-poisoned).
__global__ void cvt_w_kernel(const float* __restrict__ w, double* __restrict__ wd) {
    const int i = blockIdx.x * 256 + threadIdx.x;
    if (i < KKT * CI * CO) wd[i] = (double)w[i];
}

// normd[co] = sum_{k,ci} w^2 + 1e-8, in fp64.
__global__ void norm_kernel(const float* __restrict__ w, double* __restrict__ normd) {
    const int co = threadIdx.x;  // 0..127
    double s = 0.0;
    for (int i = 0; i < KKT * CI; ++i) {
        const double v = (double)w[i * CO + co];
        s = fma(v, v, s);
    }
    normd[co] = s + 1e-8;
}

template <bool USE_WD>
__global__ __launch_bounds__(256) void conv_lif_kernel(
    const float*  __restrict__ x,       // [32,64,64,64]
    const float*  __restrict__ mem,     // [32,128,64,64]
    const float*  __restrict__ w32,     // [9,64,128] fp32 (fallback)
    const double* __restrict__ wd,      // [9,64,128] fp64 (fast path)
    const float*  __restrict__ beta_p,  // [1]
    const float*  __restrict__ bias,    // [128]
    const double* __restrict__ normd,   // [128] = norm + 1e-8
    float* __restrict__ out_spk,        // [32,128,64,64]
    float* __restrict__ out_mem)        // [32,128,64,64]
{
    const int ix  = threadIdx.x;                    // 0..63 (coalesced along W)
    const int iy  = blockIdx.x * 4 + threadIdx.y;   // 0..63
    const int co0 = blockIdx.y * 8;                 // 0..120  (8 Cout per thread)
    const int n   = blockIdx.z;                     // 0..31

    // 9 tap offsets + validity (loop-invariant over ci).
    bool valid[9];
    int  xoff[9];
    #pragma unroll
    for (int kh = 0; kh < 3; ++kh) {
        const int yy = iy + kh - 1;
        const bool yok = (unsigned)yy < (unsigned)HH;
        #pragma unroll
        for (int kw = 0; kw < 3; ++kw) {
            const int xx = ix + kw - 1;
            const int t = kh * 3 + kw;
            valid[t] = yok && ((unsigned)xx < (unsigned)WW);
            xoff[t]  = yy * WW + xx;
        }
    }

    double acc[8];
    #pragma unroll
    for (int j = 0; j < 8; ++j) acc[j] = 0.0;

    const float* xbase = x + (size_t)n * CI * HH * WW;

    #pragma unroll 2
    for (int ci = 0; ci < CI; ++ci) {
        const float* xc = xbase + (size_t)ci * HH * WW;

        // 9 x values: load+select+convert once, reused across 8 Cout.
        double xd[9];
        #pragma unroll
        for (int t = 0; t < 9; ++t)
            xd[t] = valid[t] ? (double)xc[xoff[t]] : 0.0;

        #pragma unroll
        for (int t = 0; t < 9; ++t) {
            if (USE_WD) {
                // wave-uniform address -> scalar (s_load) path, SGPR operands
                const double* wt = wd + ((size_t)t * CI + ci) * CO + co0;
                #pragma unroll
                for (int j = 0; j < 8; ++j)
                    acc[j] = fma(xd[t], wt[j], acc[j]);
            } else {
                const float* wt = w32 + ((size_t)t * CI + ci) * CO + co0;
                #pragma unroll
                for (int j = 0; j < 8; ++j)
                    acc[j] = fma(xd[t], (double)wt[j], acc[j]);
            }
        }
    }

    // Epilogue in fp64: LIF update + multi-threshold spike.
    const double beta = (double)beta_p[0];
    const double omb  = 1.0 - beta;
    const size_t plane = (size_t)HH * WW;
    const size_t base  = (((size_t)n * CO + co0) * HH + iy) * WW + ix;

    #pragma unroll
    for (int j = 0; j < 8; ++j) {
        const size_t idx = base + (size_t)j * plane;
        const double nm   = (double)mem[idx] * beta + acc[j] * omb;
        const double mthr = nm / normd[co0 + j] - (double)bias[co0 + j];
        const int s = (mthr > 0.0) + (mthr > 1.0) + (mthr > 2.0) + (mthr > 3.0);
        out_spk[idx] = (float)s;
        out_mem[idx] = (s > 0) ? 0.0f : (float)nm;
    }
}

extern "C" void kernel_launch(void* const* d_in, const int* in_sizes, int n_in,
                              void* d_out, int out_size, void* d_ws, size_t ws_size,
                              hipStream_t stream) {
    const float* x      = (const float*)d_in[0];
    const float* mem    = (const float*)d_in[1];
    const float* w      = (const float*)d_in[2];
    const float* beta_p = (const float*)d_in[3];
    const float* bias   = (const float*)d_in[4];
    // d_in[5] = bs (=32), compile-time constant here

    float* out_spk = (float*)d_out;
    float* out_mem = out_spk + (size_t)NB * CO * HH * WW;

    const size_t wd_bytes   = (size_t)KKT * CI * CO * sizeof(double); // 589,824
    const size_t norm_bytes = (size_t)CO * sizeof(double);
    const bool use_wd = ws_size >= wd_bytes + norm_bytes;

    double* wd;
    double* normd;
    if (use_wd) {
        wd    = (double*)d_ws;
        normd = (double*)((char*)d_ws + wd_bytes);
    } else {
        wd    = nullptr;
        normd = (double*)d_ws;
    }

    norm_kernel<<<1, CO, 0, stream>>>(w, normd);
    if (use_wd) {
        cvt_w_kernel<<<(KKT * CI * CO + 255) / 256, 256, 0, stream>>>(w, wd);
    }

    dim3 block(WW, 4, 1);               // 256 threads
    dim3 grid(HH / 4, CO / 8, NB);      // 16 x 16 x 32 blocks
    if (use_wd) {
        conv_lif_kernel<true><<<grid, block, 0, stream>>>(
            x, mem, w, wd, beta_p, bias, normd, out_spk, out_mem);
    } else {
        conv_lif_kernel<false><<<grid, block, 0, stream>>>(
            x, mem, w, wd, beta_p, bias, normd, out_spk, out_mem);
    }
}

// Round 4
// 608.707 us; speedup vs baseline: 2.3195x; 1.8595x over previous
//
#include <hip/hip_runtime.h>

// SparseSpikingConv2D — Round 3: fp32 direct conv + fp64 boundary fixup.
// The harness referee recomputes in fp64; spike = hard threshold, so fp32
// ordering noise can flip pixels whose mthr is within ~1e-5 of a threshold.
// Pass A (fp32, fast): conv + LIF + spike; flags pixels with
// |mthr - d| < 2e-4 (deterministic fp32 chain error bound is ~4e-5 on mthr).
// Pass B (fp64, tiny): exact recompute of the ~13K flagged pixels.
// fp32 fma issue floor: 123 us. R2 (all-fp64) was 1000 us.

constexpr int CIc = 64, COc = 128, HHc = 64, WWc = 64, NBc = 32;
constexpr float EPSB = 2e-4f;        // borderline band on mthr
constexpr unsigned CAPc = 1u << 20;  // fixup list capacity

// workspace layout (bytes)
constexpr size_t O_CNT   = 0;                    // 1 uint (padded 16)
constexpr size_t O_NORMD = 16;                   // 128 double
constexpr size_t O_RNORM = O_NORMD + 1024;       // 128 float
constexpr size_t O_WDT   = O_RNORM + 512;        // [co][t][ci] double = 589824 B
constexpr size_t O_LIST  = O_WDT + 589824;       // CAPc uint
constexpr size_t WS_NEED = O_LIST + (size_t)CAPc * 4;

// normd = sum w^2 + 1e-8 (fp64), rnormf = 1/normd (fp32); also zero counter.
__global__ void norm_prep(const float* __restrict__ w, double* __restrict__ normd,
                          float* __restrict__ rnormf, unsigned* __restrict__ counter) {
    const int co = threadIdx.x;  // 0..127
    double s = 0.0;
    for (int i = 0; i < 9 * CIc; ++i) {
        const double v = (double)w[i * COc + co];
        s = fma(v, v, s);
    }
    s += 1e-8;
    normd[co]  = s;
    rnormf[co] = (float)(1.0 / s);
    if (co == 0) counter[0] = 0u;
}

// wdT[co][t][ci] = (double)w[t][ci][co]  (coalesced-by-ci reads in pass B)
__global__ void wT_prep(const float* __restrict__ w, double* __restrict__ wdT) {
    const int i = blockIdx.x * 256 + threadIdx.x;  // over 9*64*128 = 73728
    if (i >= 9 * CIc * COc) return;
    const int co = i & 127, ci = (i >> 7) & 63, t = i >> 13;
    wdT[((size_t)co * 9 + t) * CIc + ci] = (double)w[i];
}

// ---- Pass A: fp32 conv + LIF + spike + borderline flagging ----
// block (64,4): 64 x-lanes, 4 y-rows; each thread: 1 pixel x 32 Cout.
// grid (16 y-blocks, 4 co-blocks, 32 n).
__global__ __launch_bounds__(256) void convA(
    const float* __restrict__ x,       // [32,64,64,64]
    const float* __restrict__ mem,     // [32,128,64,64]
    const float* __restrict__ w,       // [9,64,128]
    const float* __restrict__ beta_p,
    const float* __restrict__ bias,
    const float* __restrict__ rnormf,
    float* __restrict__ out_spk, float* __restrict__ out_mem,
    unsigned* __restrict__ counter, unsigned* __restrict__ list)
{
    const int ix  = threadIdx.x;                   // lane (blockDim.x == 64)
    const int iy  = blockIdx.x * 4 + threadIdx.y;  // wave-uniform
    const int co0 = blockIdx.y * 32;               // block-uniform -> s_load weights
    const int n   = blockIdx.z;

    int  yc[3]; bool yv[3];
    #pragma unroll
    for (int dy = 0; dy < 3; ++dy) {
        const int yy = iy + dy - 1;
        yv[dy] = (unsigned)yy < (unsigned)HHc;
        yc[dy] = min(max(yy, 0), HHc - 1);
    }
    const bool lane0 = (ix == 0), lane63 = (ix == 63);

    float acc[32];
    #pragma unroll
    for (int j = 0; j < 32; ++j) acc[j] = 0.0f;

    const float* xb = x + (size_t)n * CIc * HHc * WWc;

    #pragma unroll 2
    for (int ci = 0; ci < CIc; ++ci) {
        const float* xc = xb + (size_t)ci * HHc * WWc;
        #pragma unroll
        for (int dy = 0; dy < 3; ++dy) {
            float c = xc[yc[dy] * WWc + ix];
            c = yv[dy] ? c : 0.0f;
            float l = __shfl_up(c, 1);   if (lane0)  l = 0.0f;  // tap dx=0 uses x-1
            float r = __shfl_down(c, 1); if (lane63) r = 0.0f;  // tap dx=2 uses x+1
            const float* w0 = w + ((size_t)(dy * 3 + 0) * CIc + ci) * COc + co0;
            const float* w1 = w + ((size_t)(dy * 3 + 1) * CIc + ci) * COc + co0;
            const float* w2 = w + ((size_t)(dy * 3 + 2) * CIc + ci) * COc + co0;
            #pragma unroll
            for (int j = 0; j < 32; ++j) {
                acc[j] = fmaf(l, w0[j], acc[j]);
                acc[j] = fmaf(c, w1[j], acc[j]);
                acc[j] = fmaf(r, w2[j], acc[j]);
            }
        }
    }

    const float beta = beta_p[0];
    const float omb  = 1.0f - beta;
    const size_t base = (((size_t)n * COc + co0) * HHc + iy) * WWc + ix;

    #pragma unroll
    for (int j = 0; j < 32; ++j) {
        const size_t idx = base + (size_t)j * (HHc * WWc);
        const float nm   = fmaf(mem[idx], beta, acc[j] * omb);
        const float mthr = fmaf(nm, rnormf[co0 + j], -bias[co0 + j]);
        const int s = (mthr > 0.f) + (mthr > 1.f) + (mthr > 2.f) + (mthr > 3.f);
        out_spk[idx] = (float)s;
        out_mem[idx] = (s > 0) ? 0.0f : nm;

        const bool fl = (fabsf(mthr) < EPSB) | (fabsf(mthr - 1.f) < EPSB) |
                        (fabsf(mthr - 2.f) < EPSB) | (fabsf(mthr - 3.f) < EPSB);
        const unsigned long long msk = __ballot(fl);
        if (msk) {
            unsigned wbase = 0;
            const int cnt = __popcll(msk);
            if (lane0) wbase = atomicAdd(counter, (unsigned)cnt);
            wbase = __shfl(wbase, 0);
            if (fl) {
                const unsigned pos =
                    wbase + (unsigned)__popcll(msk & ((1ull << ix) - 1ull));
                if (pos < CAPc) list[pos] = (unsigned)idx;
            }
        }
    }
}

// ---- Pass B: exact fp64 recompute of flagged pixels (wave per pixel, lane=ci) ----
__global__ __launch_bounds__(256) void fixB(
    const float* __restrict__ x, const float* __restrict__ mem,
    const float* __restrict__ beta_p, const float* __restrict__ bias,
    const double* __restrict__ normd, const double* __restrict__ wdT,
    const unsigned* __restrict__ counter, const unsigned* __restrict__ list,
    float* __restrict__ out_spk, float* __restrict__ out_mem)
{
    const int lane  = threadIdx.x & 63;
    const int wave  = blockIdx.x * 4 + (threadIdx.x >> 6);
    const int nwave = gridDim.x * 4;
    const unsigned cnt = min(counter[0], CAPc);
    const double beta = (double)beta_p[0];
    const double omb  = 1.0 - beta;

    for (unsigned p = wave; p < cnt; p += nwave) {
        const unsigned idx = list[p];
        const int xp = idx & 63, yp = (idx >> 6) & 63;
        const int co = (idx >> 12) & 127, n = idx >> 19;

        const float*  xc = x + ((size_t)n * CIc + lane) * (HHc * WWc);
        const double* wt = wdT + (size_t)co * 9 * CIc + lane;

        double a = 0.0;
        #pragma unroll
        for (int t = 0; t < 9; ++t) {
            const int yy = yp + t / 3 - 1, xx = xp + t % 3 - 1;
            const bool v = ((unsigned)yy < 64u) && ((unsigned)xx < 64u);
            const int yyc = min(max(yy, 0), 63), xxc = min(max(xx, 0), 63);
            const double xv = v ? (double)xc[yyc * WWc + xxc] : 0.0;
            a = fma(xv, wt[t * CIc], a);
        }
        #pragma unroll
        for (int off = 32; off; off >>= 1) a += __shfl_xor(a, off);

        if (lane == 0) {
            const double nm   = (double)mem[idx] * beta + a * omb;
            const double mthr = nm / normd[co] - (double)bias[co];
            const int s = (mthr > 0.) + (mthr > 1.) + (mthr > 2.) + (mthr > 3.);
            out_spk[idx] = (float)s;
            out_mem[idx] = (s > 0) ? 0.0f : (float)nm;
        }
    }
}

// ---- Fallback (ws too small): R2-style all-fp64 direct conv ----
__global__ __launch_bounds__(256) void conv_fp64_fb(
    const float* __restrict__ x, const float* __restrict__ mem,
    const float* __restrict__ w, const float* __restrict__ beta_p,
    const float* __restrict__ bias, const double* __restrict__ normd,
    float* __restrict__ out_spk, float* __restrict__ out_mem)
{
    const int ix = threadIdx.x, iy = blockIdx.x * 4 + threadIdx.y;
    const int co0 = blockIdx.y * 8, n = blockIdx.z;
    bool valid[9]; int xoff[9];
    #pragma unroll
    for (int kh = 0; kh < 3; ++kh) {
        const int yy = iy + kh - 1;
        #pragma unroll
        for (int kw = 0; kw < 3; ++kw) {
            const int xx = ix + kw - 1, t = kh * 3 + kw;
            valid[t] = ((unsigned)yy < 64u) && ((unsigned)xx < 64u);
            xoff[t]  = yy * WWc + xx;
        }
    }
    double acc[8];
    #pragma unroll
    for (int j = 0; j < 8; ++j) acc[j] = 0.0;
    const float* xb = x + (size_t)n * CIc * HHc * WWc;
    for (int ci = 0; ci < CIc; ++ci) {
        const float* xc = xb + (size_t)ci * HHc * WWc;
        #pragma unroll
        for (int t = 0; t < 9; ++t) {
            const double xv = valid[t] ? (double)xc[xoff[t]] : 0.0;
            const float* wt = w + ((size_t)t * CIc + ci) * COc + co0;
            #pragma unroll
            for (int j = 0; j < 8; ++j) acc[j] = fma(xv, (double)wt[j], acc[j]);
        }
    }
    const double beta = (double)beta_p[0], omb = 1.0 - beta;
    const size_t base = (((size_t)n * COc + co0) * HHc + iy) * WWc + ix;
    #pragma unroll
    for (int j = 0; j < 8; ++j) {
        const size_t idx = base + (size_t)j * (HHc * WWc);
        const double nm   = (double)mem[idx] * beta + acc[j] * omb;
        const double mthr = nm / normd[co0 + j] - (double)bias[co0 + j];
        const int s = (mthr > 0.) + (mthr > 1.) + (mthr > 2.) + (mthr > 3.);
        out_spk[idx] = (float)s;
        out_mem[idx] = (s > 0) ? 0.0f : (float)nm;
    }
}

extern "C" void kernel_launch(void* const* d_in, const int* in_sizes, int n_in,
                              void* d_out, int out_size, void* d_ws, size_t ws_size,
                              hipStream_t stream) {
    const float* x      = (const float*)d_in[0];
    const float* mem    = (const float*)d_in[1];
    const float* w      = (const float*)d_in[2];
    const float* beta_p = (const float*)d_in[3];
    const float* bias   = (const float*)d_in[4];

    float* out_spk = (float*)d_out;
    float* out_mem = out_spk + (size_t)NBc * COc * HHc * WWc;

    char* ws = (char*)d_ws;
    unsigned* counter = (unsigned*)(ws + O_CNT);
    double*   normd   = (double*)(ws + O_NORMD);
    float*    rnormf  = (float*)(ws + O_RNORM);
    double*   wdT     = (double*)(ws + O_WDT);
    unsigned* list    = (unsigned*)(ws + O_LIST);

    if (ws_size >= WS_NEED) {
        norm_prep<<<1, COc, 0, stream>>>(w, normd, rnormf, counter);
        wT_prep<<<(9 * CIc * COc + 255) / 256, 256, 0, stream>>>(w, wdT);

        dim3 blkA(WWc, 4, 1);              // 256 threads
        dim3 grdA(HHc / 4, COc / 32, NBc); // 16 x 4 x 32
        convA<<<grdA, blkA, 0, stream>>>(x, mem, w, beta_p, bias, rnormf,
                                         out_spk, out_mem, counter, list);
        fixB<<<1024, 256, 0, stream>>>(x, mem, beta_p, bias, normd, wdT,
                                       counter, list, out_spk, out_mem);
    } else {
        // minimal-ws fallback: all-fp64 direct conv (R2 structure)
        norm_prep<<<1, COc, 0, stream>>>(w, normd, rnormf, counter);
        dim3 blk(WWc, 4, 1);
        dim3 grd(HHc / 4, COc / 8, NBc);
        conv_fp64_fb<<<grd, blk, 0, stream>>>(x, mem, w, beta_p, bias, normd,
                                              out_spk, out_mem);
    }
}

// Round 5
// 592.673 us; speedup vs baseline: 2.3822x; 1.0271x over previous
//
#include <hip/hip_runtime.h>

// SparseSpikingConv2D — Round 4: fp32 conv with LDS-staged weights + fp64 fixup.
// R3 post-mortem: weights via wave-uniform s_load chains; 96 floats/dy ~= whole
// free SGPR budget (SGPR=112) -> no double buffering -> lgkmcnt serialization
// (VALUBusy 37%). Fix: stage the 16-cout weight slice (36 KB) in LDS, read with
// broadcast ds_read_b128 (conflict-free), prefetch in VGPRs.
// Pass A fp32 + borderline flagging (|mthr-d| < 2e-4); Pass B exact fp64 redo.

constexpr int CIc = 64, COc = 128, HHc = 64, WWc = 64, NBc = 32;
constexpr float EPSB = 2e-4f;        // borderline band on mthr
constexpr unsigned CAPc = 1u << 20;  // fixup list capacity

// workspace layout (bytes)
constexpr size_t O_CNT   = 0;                    // 1 uint (padded 16)
constexpr size_t O_NORMD = 16;                   // 128 double
constexpr size_t O_RNORM = O_NORMD + 1024;       // 128 float
constexpr size_t O_WDT   = O_RNORM + 512;        // [co][t][ci] double = 589824 B
constexpr size_t O_LIST  = O_WDT + 589824;       // CAPc uint
constexpr size_t WS_NEED = O_LIST + (size_t)CAPc * 4;

__global__ void norm_prep(const float* __restrict__ w, double* __restrict__ normd,
                          float* __restrict__ rnormf, unsigned* __restrict__ counter) {
    const int co = threadIdx.x;  // 0..127
    double s = 0.0;
    for (int i = 0; i < 9 * CIc; ++i) {
        const double v = (double)w[i * COc + co];
        s = fma(v, v, s);
    }
    s += 1e-8;
    normd[co]  = s;
    rnormf[co] = (float)(1.0 / s);
    if (co == 0) counter[0] = 0u;
}

// wdT[co][t][ci] = (double)w[t][ci][co]
__global__ void wT_prep(const float* __restrict__ w, double* __restrict__ wdT) {
    const int i = blockIdx.x * 256 + threadIdx.x;  // over 9*64*128 = 73728
    if (i >= 9 * CIc * COc) return;
    const int co = i & 127, ci = (i >> 7) & 63, t = i >> 13;
    wdT[((size_t)co * 9 + t) * CIc + ci] = (double)w[i];
}

// ---- Pass A: fp32 conv + LIF + spike + borderline flagging ----
// block (64,8) = 512 threads; thread = 1 pixel x 16 Cout; weights in LDS.
__global__ __launch_bounds__(512, 4) void convA(
    const float* __restrict__ x,       // [32,64,64,64]
    const float* __restrict__ mem,     // [32,128,64,64]
    const float* __restrict__ w,       // [9,64,128]
    const float* __restrict__ beta_p,
    const float* __restrict__ bias,
    const float* __restrict__ rnormf,
    float* __restrict__ out_spk, float* __restrict__ out_mem,
    unsigned* __restrict__ counter, unsigned* __restrict__ list)
{
    __shared__ float lds_w[9 * CIc * 16];          // 36 KB: [t*64+ci][16 co]

    const int ix  = threadIdx.x;                   // lane 0..63
    const int iy  = blockIdx.x * 8 + threadIdx.y;  // wave-uniform row
    const int co0 = blockIdx.y * 16;
    const int n   = blockIdx.z;

    // Stage weight slice -> LDS (one-time; 2304 float4, 512 threads, 5 iters).
    {
        const int tid = threadIdx.y * 64 + threadIdx.x;
        const float4* __restrict__ wg = (const float4*)w;  // [row][32 x float4]
        float4* __restrict__ ws4 = (float4*)lds_w;         // [row][4 x float4]
        for (int q = tid; q < 9 * CIc * 4; q += 512) {
            const int row = q >> 2, c4 = q & 3;
            ws4[q] = wg[row * 32 + (co0 >> 2) + c4];
        }
    }
    __syncthreads();

    int  yc[3]; bool yv[3];
    #pragma unroll
    for (int dy = 0; dy < 3; ++dy) {
        const int yy = iy + dy - 1;
        yv[dy] = (unsigned)yy < (unsigned)HHc;
        yc[dy] = min(max(yy, 0), HHc - 1);
    }
    const bool lane0 = (ix == 0), lane63 = (ix == 63);

    float acc[16];
    #pragma unroll
    for (int j = 0; j < 16; ++j) acc[j] = 0.0f;

    const float* xb = x + (size_t)n * CIc * HHc * WWc;
    const float4* __restrict__ lw4 = (const float4*)lds_w;

    #pragma unroll 2
    for (int ci = 0; ci < CIc; ++ci) {
        const float* xc = xb + (size_t)ci * HHc * WWc;
        #pragma unroll
        for (int dy = 0; dy < 3; ++dy) {
            float c = xc[yc[dy] * WWc + ix];
            c = yv[dy] ? c : 0.0f;
            float l = __shfl_up(c, 1);   if (lane0)  l = 0.0f;  // kw=0 -> x-1
            float r = __shfl_down(c, 1); if (lane63) r = 0.0f;  // kw=2 -> x+1
            const int b0 = ((dy * 3 + 0) * CIc + ci) * 4;
            const int b1 = ((dy * 3 + 1) * CIc + ci) * 4;
            const int b2 = ((dy * 3 + 2) * CIc + ci) * 4;
            #pragma unroll
            for (int g = 0; g < 4; ++g) {
                const float4 w0 = lw4[b0 + g];
                const float4 w1 = lw4[b1 + g];
                const float4 w2 = lw4[b2 + g];
                float* a = acc + g * 4;
                a[0] = fmaf(l, w0.x, a[0]); a[1] = fmaf(l, w0.y, a[1]);
                a[2] = fmaf(l, w0.z, a[2]); a[3] = fmaf(l, w0.w, a[3]);
                a[0] = fmaf(c, w1.x, a[0]); a[1] = fmaf(c, w1.y, a[1]);
                a[2] = fmaf(c, w1.z, a[2]); a[3] = fmaf(c, w1.w, a[3]);
                a[0] = fmaf(r, w2.x, a[0]); a[1] = fmaf(r, w2.y, a[1]);
                a[2] = fmaf(r, w2.z, a[2]); a[3] = fmaf(r, w2.w, a[3]);
            }
        }
    }

    const float beta = beta_p[0];
    const float omb  = 1.0f - beta;
    const size_t base = (((size_t)n * COc + co0) * HHc + iy) * WWc + ix;

    #pragma unroll
    for (int j = 0; j < 16; ++j) {
        const size_t idx = base + (size_t)j * (HHc * WWc);
        const float nm   = fmaf(mem[idx], beta, acc[j] * omb);
        const float mthr = fmaf(nm, rnormf[co0 + j], -bias[co0 + j]);
        const int s = (mthr > 0.f) + (mthr > 1.f) + (mthr > 2.f) + (mthr > 3.f);
        out_spk[idx] = (float)s;
        out_mem[idx] = (s > 0) ? 0.0f : nm;

        const bool fl = (fabsf(mthr) < EPSB) | (fabsf(mthr - 1.f) < EPSB) |
                        (fabsf(mthr - 2.f) < EPSB) | (fabsf(mthr - 3.f) < EPSB);
        const unsigned long long msk = __ballot(fl);
        if (msk) {
            unsigned wbase = 0;
            const int cnt = __popcll(msk);
            if (lane0) wbase = atomicAdd(counter, (unsigned)cnt);
            wbase = __shfl(wbase, 0);
            if (fl) {
                const unsigned pos =
                    wbase + (unsigned)__popcll(msk & ((1ull << ix) - 1ull));
                if (pos < CAPc) list[pos] = (unsigned)idx;
            }
        }
    }
}

// ---- Pass B: exact fp64 recompute of flagged pixels (wave per pixel, lane=ci) ----
__global__ __launch_bounds__(256) void fixB(
    const float* __restrict__ x, const float* __restrict__ mem,
    const float* __restrict__ beta_p, const float* __restrict__ bias,
    const double* __restrict__ normd, const double* __restrict__ wdT,
    const unsigned* __restrict__ counter, const unsigned* __restrict__ list,
    float* __restrict__ out_spk, float* __restrict__ out_mem)
{
    const int lane  = threadIdx.x & 63;
    const int wave  = blockIdx.x * 4 + (threadIdx.x >> 6);
    const int nwave = gridDim.x * 4;
    const unsigned cnt = min(counter[0], CAPc);
    const double beta = (double)beta_p[0];
    const double omb  = 1.0 - beta;

    for (unsigned p = wave; p < cnt; p += nwave) {
        const unsigned idx = list[p];
        const int xp = idx & 63, yp = (idx >> 6) & 63;
        const int co = (idx >> 12) & 127, n = idx >> 19;

        const float*  xc = x + ((size_t)n * CIc + lane) * (HHc * WWc);
        const double* wt = wdT + (size_t)co * 9 * CIc + lane;

        double a = 0.0;
        #pragma unroll
        for (int t = 0; t < 9; ++t) {
            const int yy = yp + t / 3 - 1, xx = xp + t % 3 - 1;
            const bool v = ((unsigned)yy < 64u) && ((unsigned)xx < 64u);
            const int yyc = min(max(yy, 0), 63), xxc = min(max(xx, 0), 63);
            const double xv = v ? (double)xc[yyc * WWc + xxc] : 0.0;
            a = fma(xv, wt[t * CIc], a);
        }
        #pragma unroll
        for (int off = 32; off; off >>= 1) a += __shfl_xor(a, off);

        if (lane == 0) {
            const double nm   = (double)mem[idx] * beta + a * omb;
            const double mthr = nm / normd[co] - (double)bias[co];
            const int s = (mthr > 0.) + (mthr > 1.) + (mthr > 2.) + (mthr > 3.);
            out_spk[idx] = (float)s;
            out_mem[idx] = (s > 0) ? 0.0f : (float)nm;
        }
    }
}

// ---- Fallback (ws too small): all-fp64 direct conv ----
__global__ __launch_bounds__(256) void conv_fp64_fb(
    const float* __restrict__ x, const float* __restrict__ mem,
    const float* __restrict__ w, const float* __restrict__ beta_p,
    const float* __restrict__ bias, const double* __restrict__ normd,
    float* __restrict__ out_spk, float* __restrict__ out_mem)
{
    const int ix = threadIdx.x, iy = blockIdx.x * 4 + threadIdx.y;
    const int co0 = blockIdx.y * 8, n = blockIdx.z;
    bool valid[9]; int xoff[9];
    #pragma unroll
    for (int kh = 0; kh < 3; ++kh) {
        const int yy = iy + kh - 1;
        #pragma unroll
        for (int kw = 0; kw < 3; ++kw) {
            const int xx = ix + kw - 1, t = kh * 3 + kw;
            valid[t] = ((unsigned)yy < 64u) && ((unsigned)xx < 64u);
            xoff[t]  = yy * WWc + xx;
        }
    }
    double acc[8];
    #pragma unroll
    for (int j = 0; j < 8; ++j) acc[j] = 0.0;
    const float* xb = x + (size_t)n * CIc * HHc * WWc;
    for (int ci = 0; ci < CIc; ++ci) {
        const float* xc = xb + (size_t)ci * HHc * WWc;
        #pragma unroll
        for (int t = 0; t < 9; ++t) {
            const double xv = valid[t] ? (double)xc[xoff[t]] : 0.0;
            const float* wt = w + ((size_t)t * CIc + ci) * COc + co0;
            #pragma unroll
            for (int j = 0; j < 8; ++j) acc[j] = fma(xv, (double)wt[j], acc[j]);
        }
    }
    const double beta = (double)beta_p[0], omb = 1.0 - beta;
    const size_t base = (((size_t)n * COc + co0) * HHc + iy) * WWc + ix;
    #pragma unroll
    for (int j = 0; j < 8; ++j) {
        const size_t idx = base + (size_t)j * (HHc * WWc);
        const double nm   = (double)mem[idx] * beta + acc[j] * omb;
        const double mthr = nm / normd[co0 + j] - (double)bias[co0 + j];
        const int s = (mthr > 0.) + (mthr > 1.) + (mthr > 2.) + (mthr > 3.);
        out_spk[idx] = (float)s;
        out_mem[idx] = (s > 0) ? 0.0f : (float)nm;
    }
}

extern "C" void kernel_launch(void* const* d_in, const int* in_sizes, int n_in,
                              void* d_out, int out_size, void* d_ws, size_t ws_size,
                              hipStream_t stream) {
    const float* x      = (const float*)d_in[0];
    const float* mem    = (const float*)d_in[1];
    const float* w      = (const float*)d_in[2];
    const float* beta_p = (const float*)d_in[3];
    const float* bias   = (const float*)d_in[4];

    float* out_spk = (float*)d_out;
    float* out_mem = out_spk + (size_t)NBc * COc * HHc * WWc;

    char* ws = (char*)d_ws;
    unsigned* counter = (unsigned*)(ws + O_CNT);
    double*   normd   = (double*)(ws + O_NORMD);
    float*    rnormf  = (float*)(ws + O_RNORM);
    double*   wdT     = (double*)(ws + O_WDT);
    unsigned* list    = (unsigned*)(ws + O_LIST);

    if (ws_size >= WS_NEED) {
        norm_prep<<<1, COc, 0, stream>>>(w, normd, rnormf, counter);
        wT_prep<<<(9 * CIc * COc + 255) / 256, 256, 0, stream>>>(w, wdT);

        dim3 blkA(WWc, 8, 1);              // 512 threads
        dim3 grdA(HHc / 8, COc / 16, NBc); // 8 x 8 x 32 = 2048
        convA<<<grdA, blkA, 0, stream>>>(x, mem, w, beta_p, bias, rnormf,
                                         out_spk, out_mem, counter, list);
        fixB<<<1024, 256, 0, stream>>>(x, mem, beta_p, bias, normd, wdT,
                                       counter, list, out_spk, out_mem);
    } else {
        norm_prep<<<1, COc, 0, stream>>>(w, normd, rnormf, counter);
        dim3 blk(WWc, 4, 1);
        dim3 grd(HHc / 4, COc / 8, NBc);
        conv_fp64_fb<<<grd, blk, 0, stream>>>(x, mem, w, beta_p, bias, normd,
                                              out_spk, out_mem);
    }
}